// Round 3
// baseline (419.971 us; speedup 1.0000x reference)
//
#include <hip/hip_runtime.h>

// ---------------------------------------------------------------------------
// Kernel A: segment boundaries in SORTED domain_ids.
// starts[d]=-1 (memset 0xFF) means empty domain.
// ---------------------------------------------------------------------------
__global__ void bounds_kernel(const int* __restrict__ dids,
                              int* __restrict__ starts,
                              int* __restrict__ ends, int E) {
    int e = blockIdx.x * blockDim.x + threadIdx.x;
    if (e >= E) return;
    int d = dids[e];
    if (e == 0) {
        starts[d] = 0;
    } else {
        int dp = dids[e - 1];
        if (d != dp) {
            starts[d] = e;
            ends[dp]  = e;
        }
    }
    if (e == E - 1) ends[d] = E;
}

// ---------------------------------------------------------------------------
// Kernel B v4 (UNCHANGED — control for this round): gather + segment-sum,
// one wave per domain, 16-lane groups gather float4 rows, 4 entries per
// wave-load phase. Measured: 175 us, FETCH 505 MB, VALUBusy 25%,
// occupancy 82% -> fabric/L3 random-gather BW-bound at ~3.3 TB/s.
// ---------------------------------------------------------------------------
__global__ void seg_sum_kernel(const float* __restrict__ feat,
                               const int* __restrict__ aidx,
                               const int* __restrict__ starts,
                               const int* __restrict__ ends,
                               float* __restrict__ T, int M) {
    int wid  = (int)(((size_t)blockIdx.x * blockDim.x + threadIdx.x) >> 6);
    if (wid >= M) return;
    int lane = threadIdx.x & 63;
    int g    = lane >> 4;          // entry-phase group 0..3
    int l16  = lane & 15;          // float4 chunk within the 64-ch row
    int coff = l16 * 4;            // channel offset

    int s = starts[wid];
    int e = ends[wid];

    float4 acc = make_float4(0.f, 0.f, 0.f, 0.f);
    if (s >= 0) {
        int last = e - 1;
        for (int base = s; base < e; base += 16) {
            int rem = e - base;            // uniform, >= 1
            int ti  = base + l16;
            int idxv = aidx[ti <= last ? ti : last];
            if (rem >= 16) {
#pragma unroll
                for (int p = 0; p < 4; ++p) {
                    int row = __shfl(idxv, p * 4 + g, 64);
                    const float4 v =
                        *(const float4*)(feat + (size_t)row * 64 + coff);
                    acc.x += v.x; acc.y += v.y; acc.z += v.z; acc.w += v.w;
                }
            } else {
                int nph = (rem + 3) >> 2;  // uniform phase count
                for (int p = 0; p < nph; ++p) {
                    int t   = base + p * 4 + g;
                    int row = __shfl(idxv, p * 4 + g, 64);
                    const float4 v =
                        *(const float4*)(feat + (size_t)row * 64 + coff);
                    float w = (t <= last) ? 1.f : 0.f;
                    acc.x = fmaf(v.x, w, acc.x);
                    acc.y = fmaf(v.y, w, acc.y);
                    acc.z = fmaf(v.z, w, acc.z);
                    acc.w = fmaf(v.w, w, acc.w);
                }
            }
        }
        acc.x += __shfl_xor(acc.x, 16, 64);
        acc.y += __shfl_xor(acc.y, 16, 64);
        acc.z += __shfl_xor(acc.z, 16, 64);
        acc.w += __shfl_xor(acc.w, 16, 64);
        acc.x += __shfl_xor(acc.x, 32, 64);
        acc.y += __shfl_xor(acc.y, 32, 64);
        acc.z += __shfl_xor(acc.z, 32, 64);
        acc.w += __shfl_xor(acc.w, 32, 64);
    }
    if (g == 0)
        *(float4*)(T + (size_t)wid * 64 + coff) = acc;
}

// ---------------------------------------------------------------------------
// Proj v5: out = T @ W + b, 128-row x 128-col tile per 256-thread block,
// 8x8 register blocking per thread.
// LDS amortization vs v4: per thread per k-step 4 b128 (64 B) for 64 FMA
// = 0.5 B/FMA (v4 was 1.5 B/FMA -> LDS-throughput-bound at ~9.2k cy/block).
// All inner-loop LDS reads are broadcasts:
//   lds_t[k][r0]: 4 distinct 16B chunks/wave (16-lane broadcast), 128 B
//     apart, row stride 132 floats rotates banks by 4 -> conflict-free.
//   lds_w[k][c0]: 16 distinct 16B chunks/wave (4-lane broadcast), 2-way
//     bank aliasing = free (m136).
// FMA floor: 2.05e9 FMA / (256 CU * 128 lanes/cy * 2.4 GHz) = 26 us.
// LDS: 32 KB (W) + 33.8 KB (T) = 65.8 KB -> 2 blocks/CU, 8 waves/CU.
// ---------------------------------------------------------------------------
#define TM 128
__global__ void __launch_bounds__(256)
proj_kernel(const float* __restrict__ T,
            const float* __restrict__ W,
            const float* __restrict__ bias,
            float* __restrict__ out, int M) {
    __shared__ float lds_w[64][128];
    __shared__ float lds_t[64][TM + 4];   // stride 132 floats = 528 B (16B mult)

    int tid  = threadIdx.x;
    long row0 = (long)blockIdx.x * TM;

    // Stage W: 8192 floats = 2048 float4, 8 per thread, coalesced.
#pragma unroll
    for (int i = 0; i < 8; ++i) {
        int idx = tid + i * 256;          // 0..2047
        int k   = idx >> 5;
        int ch  = idx & 31;
        float4 wv = ((const float4*)W)[idx];
        *(float4*)&lds_w[k][ch * 4] = wv;
    }
    // Stage T transposed: 128 rows x 16 float4 chunks, 8 per thread.
#pragma unroll
    for (int i = 0; i < 8; ++i) {
        int idx = tid + i * 256;          // 0..2047
        int r   = idx >> 4;               // 0..127
        int ch  = idx & 15;
        long gr = row0 + r;
        if (gr > (long)M - 1) gr = (long)M - 1; // clamp: stores guarded
        float4 tv = ((const float4*)(T + gr * 64))[ch];
        lds_t[ch * 4 + 0][r] = tv.x;
        lds_t[ch * 4 + 1][r] = tv.y;
        lds_t[ch * 4 + 2][r] = tv.z;
        lds_t[ch * 4 + 3][r] = tv.w;
    }
    __syncthreads();

    int c0 = (tid & 15) * 8;              // 8 output cols
    int r0 = (tid >> 4) * 8;              // 8 output rows

    float acc[8][8];
#pragma unroll
    for (int r = 0; r < 8; ++r)
#pragma unroll
        for (int c = 0; c < 8; ++c) acc[r][c] = 0.f;

#pragma unroll 4
    for (int k = 0; k < 64; ++k) {
        float4 ta = *(const float4*)&lds_t[k][r0];
        float4 tb = *(const float4*)&lds_t[k][r0 + 4];
        float4 wa = *(const float4*)&lds_w[k][c0];
        float4 wb = *(const float4*)&lds_w[k][c0 + 4];
        float t[8] = {ta.x, ta.y, ta.z, ta.w, tb.x, tb.y, tb.z, tb.w};
        float w[8] = {wa.x, wa.y, wa.z, wa.w, wb.x, wb.y, wb.z, wb.w};
#pragma unroll
        for (int r = 0; r < 8; ++r)
#pragma unroll
            for (int c = 0; c < 8; ++c)
                acc[r][c] = fmaf(t[r], w[c], acc[r][c]);
    }

    float4 bva = *(const float4*)&bias[c0];
    float4 bvb = *(const float4*)&bias[c0 + 4];
#pragma unroll
    for (int r = 0; r < 8; ++r) {
        long row = row0 + r0 + r;
        if (row < M) {
            float4 o0, o1;
            o0.x = acc[r][0] + bva.x;
            o0.y = acc[r][1] + bva.y;
            o0.z = acc[r][2] + bva.z;
            o0.w = acc[r][3] + bva.w;
            o1.x = acc[r][4] + bvb.x;
            o1.y = acc[r][5] + bvb.y;
            o1.z = acc[r][6] + bvb.z;
            o1.w = acc[r][7] + bvb.w;
            *(float4*)&out[row * 128 + c0]     = o0;
            *(float4*)&out[row * 128 + c0 + 4] = o1;
        }
    }
}

extern "C" void kernel_launch(void* const* d_in, const int* in_sizes, int n_in,
                              void* d_out, int out_size, void* d_ws, size_t ws_size,
                              hipStream_t stream) {
    const float* feat = (const float*)d_in[0];   // [N_ATOMS, 64] f32
    const int*   aidx = (const int*)d_in[1];     // [E] int
    const int*   dids = (const int*)d_in[2];     // [E] int (sorted)
    const float* W    = (const float*)d_in[4];   // [64, 128] f32
    const float* bias = (const float*)d_in[5];   // [128] f32
    float*       out  = (float*)d_out;           // [M, 128] f32

    int E = in_sizes[1];
    int M = out_size / 128;

    float* T = (float*)d_ws;                     // [M, 64] f32 = 64 MB
    size_t tbytes = (size_t)M * 64 * sizeof(float);
    size_t bbytes = 2 * (size_t)M * sizeof(int);

    int* starts;
    if (ws_size >= tbytes + bbytes) {
        starts = (int*)((char*)d_ws + tbytes);
    } else {
        // Stash boundaries in the tail of d_out; proj overwrites them only
        // after seg_sum consumed them (same-stream serialization).
        starts = (int*)((char*)d_out + (size_t)out_size * sizeof(float) - bbytes);
    }
    int* ends = starts + M;

    hipMemsetAsync(starts, 0xFF, bbytes, stream);

    bounds_kernel<<<(E + 255) / 256, 256, 0, stream>>>(dids, starts, ends, E);

    int waves_blocks = (int)(((size_t)M * 64 + 255) / 256);
    seg_sum_kernel<<<waves_blocks, 256, 0, stream>>>(feat, aidx, starts, ends, T, M);

    proj_kernel<<<(M + TM - 1) / TM, 256, 0, stream>>>(T, W, bias, out, M);
}